// Round 11
// baseline (1759.326 us; speedup 1.0000x reference)
//
#include <hip/hip_runtime.h>
#include <cstddef>

constexpr int H  = 512;   // hidden
constexpr int F  = 21;    // features
constexpr int T  = 28;    // output steps
constexpr int PB = 128;   // producer blocks
constexpr int NB = PB + 1;// + 1 dedicated y-writer block
constexpr int NT = 256;   // 4 waves/block -> 512 producer waves, 1 row/wave
constexpr int NW = NT / 64;
constexpr int NC = 3 + 3 * T;  // phase counters: enc0..2, then (t,l)
constexpr int CS = 16;         // counter stride (one per cache line region)

#define SCOPE_AGENT __HIP_MEMORY_SCOPE_AGENT

// Counter-notify dataflow: producer wave stores its float (relaxed agent),
// then release-fetch_adds the phase counter (release drains the store to the
// coherence point first -> counter==512 implies all 512 elements visible).
// Consumers spin on ONE 4B counter (O(1) poll transactions vs 64K/round for
// per-element tags), then do a single coalesced data burst. Data arrays need
// no inter-replay reset; only counters are zeroed at exit.
__device__ float    g_h[2][3][H];   // h state ping-pong per layer
__device__ float    g_hy[T][H];     // step-unique h2 copies for the y-writer
__device__ unsigned g_cnt[NC * CS]; // phase counters (padded)
__device__ unsigned g_exit;

__device__ __forceinline__ int cidx(int t, int l) { return 3 + 3 * t + l; }

struct P {
  const float *x, *py, *eW0, *eW1, *eW2, *ebih, *ebhh;
  const float *dW0, *dW1, *dW2, *dWhh, *dbih, *dbhh, *outW, *outb;
  float* out;
};

__device__ __forceinline__ float sigm(float v)  { return 1.0f / (1.0f + __expf(-v)); }
__device__ __forceinline__ float tanh_f(float v){ return 1.0f - 2.0f / (__expf(2.0f * v) + 1.0f); }

__device__ __forceinline__ float4 wredsum4(float4 v) {
#pragma unroll
  for (int off = 32; off > 0; off >>= 1) {
    v.x += __shfl_xor(v.x, off, 64);
    v.y += __shfl_xor(v.y, off, 64);
    v.z += __shfl_xor(v.z, off, 64);
    v.w += __shfl_xor(v.w, off, 64);
  }
  return v;
}
__device__ __forceinline__ float wredsum1(float v) {
#pragma unroll
  for (int off = 32; off > 0; off >>= 1) v += __shfl_xor(v, off, 64);
  return v;
}

// Publish one element + bump the phase counter (release orders the store).
__device__ __forceinline__ void pub(float* slot, float v, int ci) {
  __hip_atomic_store(slot, v, __ATOMIC_RELAXED, SCOPE_AGENT);
  (void)__hip_atomic_fetch_add(&g_cnt[ci * CS], 1u, __ATOMIC_RELEASE, SCOPE_AGENT);
}
// Two-slot publish (S2: main chain + y-writer copy), one counter bump.
__device__ __forceinline__ void pub2(float* s1, float* s2, float v, int ci) {
  __hip_atomic_store(s1, v, __ATOMIC_RELAXED, SCOPE_AGENT);
  __hip_atomic_store(s2, v, __ATOMIC_RELAXED, SCOPE_AGENT);
  (void)__hip_atomic_fetch_add(&g_cnt[ci * CS], 1u, __ATOMIC_RELEASE, SCOPE_AGENT);
}

// Wait until phase ci complete (counter == 512). Single-thread spin.
__device__ __forceinline__ void cwait(int ci) {
  if (threadIdx.x == 0) {
    const unsigned* c = &g_cnt[ci * CS];
    int guard = 0;
    while (__hip_atomic_load(c, __ATOMIC_RELAXED, SCOPE_AGENT) < 512u &&
           ++guard < (1 << 22)) {}
  }
  __syncthreads();
}

// One coalesced burst: thread i loads 8B pair {2i, 2i+1} (agent-coherent),
// writes LDS. Trailing barrier. Call only after cwait(ci) for the producer.
__device__ __forceinline__ void ldvec(const float* __restrict__ A,
                                      float* __restrict__ dst) {
  const int i = threadIdx.x;
  unsigned long long v =
      __hip_atomic_load((const unsigned long long*)A + i, __ATOMIC_RELAXED, SCOPE_AGENT);
  union { unsigned long long u; float f[2]; } c; c.u = v;
  dst[2 * i] = c.f[0]; dst[2 * i + 1] = c.f[1];
  __syncthreads();
}

// 4-gate weight fragment block: 8 float4 = 64B/lane per matrix.
struct W8 { float4 a[4]; float4 b[4]; };

__device__ __forceinline__ W8 ldw_g(const float* __restrict__ W, int r, int lane) {
  W8 o;
#pragma unroll
  for (int g = 0; g < 4; ++g) {
    const float* q = W + (size_t)(g * H + r) * H + lane * 8;
    o.a[g] = *(const float4*)q;
    o.b[g] = *(const float4*)(q + 4);
  }
  return o;
}
__device__ __forceinline__ W8 ldw_lds(const float* sM, int w, int lane) {
  W8 o;
#pragma unroll
  for (int g = 0; g < 4; ++g) {
    const float* q = sM + (w * 4 + g) * H + lane * 8;
    o.a[g] = *(const float4*)q;
    o.b[g] = *(const float4*)(q + 4);
  }
  return o;
}
__device__ __forceinline__ void fma8(const W8& wt, const float4& x0, const float4& x1,
                                     float s[4]) {
#pragma unroll
  for (int g = 0; g < 4; ++g) {
    s[g] += wt.a[g].x * x0.x + wt.a[g].y * x0.y + wt.a[g].z * x0.z + wt.a[g].w * x0.w
          + wt.b[g].x * x1.x + wt.b[g].y * x1.y + wt.b[g].z * x1.z + wt.b[g].w * x1.w;
  }
}

__device__ __forceinline__ float cellup(const float4& v, const float b[4], float& c) {
  float cn = sigm(v.y + b[1]) * c + sigm(v.x + b[0]) * tanh_f(v.z + b[2]);
  c = cn;
  return sigm(v.w + b[3]) * tanh_f(cn);
}

__device__ __forceinline__ void write_y_frag(const P& p, int trow, int w, int lane,
                                             const float4& h0, const float4& h1,
                                             const float* sYe) {
  for (int j = w; j < F; j += NW) {
    const float* q = p.outW + (size_t)j * (2 * H) + lane * 8;
    float4 w0 = *(const float4*)q;
    float4 w1 = *(const float4*)(q + 4);
    float s = w0.x * h0.x + w0.y * h0.y + w0.z * h0.z + w0.w * h0.w
            + w1.x * h1.x + w1.y * h1.y + w1.z * h1.z + w1.w * h1.w;
    s = wredsum1(s);
    if (lane == 0) p.out[trow * F + j] = s + sYe[j];
  }
}

__global__ __launch_bounds__(NT, 1)
void k_flow(P p) {
  const int lane = threadIdx.x & 63;
  const int w    = threadIdx.x >> 6;

  __shared__ float sM[NW * 4 * H];   // 32 KB: producer rows of M = dW0[:,:F]@outW_h
  __shared__ float sBuf[2][H];       // 4 KB: double-buffered staged vector
  __shared__ float senc[H];          // persistent encoder output
  __shared__ float sYe[F + 3];       // y_e = outW_e@enc + outb
  __shared__ int   s_last;

  if (blockIdx.x == PB) {
    // ================= Dedicated y-writer block (off critical path) ========
    cwait(2);                       // encoder output ready
    ldvec(g_h[1][2], senc);
    {
      float4 e0 = *(const float4*)(senc + lane * 8);
      float4 e1 = *(const float4*)(senc + lane * 8 + 4);
      for (int j = w; j < F; j += NW) {
        const float* q = p.outW + (size_t)j * (2 * H) + H + lane * 8;
        float4 w0 = *(const float4*)q;
        float4 w1 = *(const float4*)(q + 4);
        float s = w0.x * e0.x + w0.y * e0.y + w0.z * e0.z + w0.w * e0.w
                + w1.x * e1.x + w1.y * e1.y + w1.z * e1.z + w1.w * e1.w;
        s = wredsum1(s);
        if (lane == 0) sYe[j] = s + p.outb[j];
      }
      __syncthreads();
    }
    for (int t = 0; t < T; ++t) {
      float* xb = sBuf[t & 1];
      cwait(cidx(t, 2));
      ldvec(g_hy[t], xb);           // step-unique slot
      float4 h20 = *(const float4*)(xb + lane * 8);
      float4 h21 = *(const float4*)(xb + lane * 8 + 4);
      write_y_frag(p, t, w, lane, h20, h21, sYe);
    }
  } else {
    // ========================= Producer blocks =============================
    const int r = blockIdx.x * NW + w;  // 1 row/wave, fixed mapping (L2 locality)

    float c0 = 0.f, c1 = 0.f, c2 = 0.f;
    float b00[4], b0p[4], b1s[4], b2s[4];  // lane-0-meaningful biases
    float sOld0[4] = {0, 0, 0, 0}, sOld1[4] = {0, 0, 0, 0}, sOld2[4] = {0, 0, 0, 0};
    int bi = 0;

    // ---- Encoder layer 0: h=c=0 -> Whh zero, f-gate dead. Counter 0. ----
    {
      float s0 = 0.f, s1 = 0.f, s2 = 0.f, s3 = 0.f;
      if (lane < F) {
        const float xv = p.x[lane];
        s0 = p.eW0[(size_t)(0 * H + r) * F + lane] * xv;
        s1 = p.eW0[(size_t)(1 * H + r) * F + lane] * xv;
        s2 = p.eW0[(size_t)(2 * H + r) * F + lane] * xv;
        s3 = p.eW0[(size_t)(3 * H + r) * F + lane] * xv;
      }
      float4 v = wredsum4(make_float4(s0, s1, s2, s3));
      if (lane == 0) {
        const float* bi_ = p.ebih + r;
        const float* bh_ = p.ebhh + r;
        float cn = sigm(v.x + bi_[0] + bh_[0]) * tanh_f(v.z + bi_[2 * H] + bh_[2 * H]);
        c0 = cn;
        pub(&g_h[1][0][r], sigm(v.w + bi_[3 * H] + bh_[3 * H]) * tanh_f(cn), 0);
      }
    }

    // ---- Build sM while other blocks finish enc0 (input-independent) ----
    {
      float4 mA[4], mB[4];
#pragma unroll
      for (int g = 0; g < 4; ++g) {
        mA[g] = make_float4(0.f, 0.f, 0.f, 0.f);
        mB[g] = make_float4(0.f, 0.f, 0.f, 0.f);
      }
      for (int f = 0; f < F; ++f) {
        const float* q = p.outW + (size_t)f * (2 * H) + lane * 8;
        const float4 oa = *(const float4*)q;
        const float4 ob = *(const float4*)(q + 4);
#pragma unroll
        for (int g = 0; g < 4; ++g) {
          const float wf = p.dW0[(size_t)(g * H + r) * (H + F) + f];
          mA[g].x += wf * oa.x; mA[g].y += wf * oa.y; mA[g].z += wf * oa.z; mA[g].w += wf * oa.w;
          mB[g].x += wf * ob.x; mB[g].y += wf * ob.y; mB[g].z += wf * ob.z; mB[g].w += wf * ob.w;
        }
      }
#pragma unroll
      for (int g = 0; g < 4; ++g) {
        *(float4*)(sM + (w * 4 + g) * H + lane * 8)     = mA[g];
        *(float4*)(sM + (w * 4 + g) * H + lane * 8 + 4) = mB[g];
      }
    }
#pragma unroll
    for (int g = 0; g < 4; ++g) {
      b1s[g] = p.dbih[4 * H + g * H + r] + p.dbhh[4 * H + g * H + r];
      b2s[g] = p.dbih[8 * H + g * H + r] + p.dbhh[8 * H + g * H + r];
    }

    // ---- Encoder layer 1 (stages h0_enc into sBuf[0]; kept for decoder t=0) ----
    {
      W8 wt = ldw_g(p.eW1, r, lane);  // prefetch before wait
      cwait(0);
      ldvec(g_h[1][0], sBuf[0]);
      float4 a0 = *(const float4*)(sBuf[0] + lane * 8);
      float4 a1 = *(const float4*)(sBuf[0] + lane * 8 + 4);
      float s[4] = {0.f, 0.f, 0.f, 0.f};
      fma8(wt, a0, a1, s);
      float4 v = wredsum4(make_float4(s[0], s[1], s[2], s[3]));
      if (lane == 0) {
        const float* bi_ = p.ebih + 4 * H + r;
        const float* bh_ = p.ebhh + 4 * H + r;
        float cn = sigm(v.x + bi_[0] + bh_[0]) * tanh_f(v.z + bi_[2 * H] + bh_[2 * H]);
        c1 = cn;
        pub(&g_h[1][1][r], sigm(v.w + bi_[3 * H] + bh_[3 * H]) * tanh_f(cn), 1);
      }
    }

    // ---- Encoder layer 2 -> enc_out; extra: sOld1 = Whh1@h1_enc (for S1(0)) ----
    {
      W8 wt  = ldw_g(p.eW2, r, lane);
      W8 wh1 = ldw_g(p.dWhh + (size_t)4 * H * H, r, lane);
      cwait(1);
      ldvec(g_h[1][1], sBuf[1]);
      float4 a0 = *(const float4*)(sBuf[1] + lane * 8);
      float4 a1 = *(const float4*)(sBuf[1] + lane * 8 + 4);
      float s[4] = {0.f, 0.f, 0.f, 0.f};
      fma8(wt, a0, a1, s);
      float4 v = wredsum4(make_float4(s[0], s[1], s[2], s[3]));
      if (lane == 0) {
        const float* bi_ = p.ebih + 8 * H + r;
        const float* bh_ = p.ebhh + 8 * H + r;
        float cn = sigm(v.x + bi_[0] + bh_[0]) * tanh_f(v.z + bi_[2 * H] + bh_[2 * H]);
        c2 = cn;
        pub(&g_h[1][2][r], sigm(v.w + bi_[3 * H] + bh_[3 * H]) * tanh_f(cn), 2);
      }
      fma8(wh1, a0, a1, sOld1);
    }

    // ---- Setup: senc, y_e, base0 constants; extra: sOld2 = Whh2@enc ----
    {
      W8 wh2 = ldw_g(p.dWhh + (size_t)8 * H * H, r, lane);
      cwait(2);
      ldvec(g_h[1][2], senc);        // senc persists (read-only afterwards)
      float4 e0 = *(const float4*)(senc + lane * 8);
      float4 e1 = *(const float4*)(senc + lane * 8 + 4);
      for (int j = w; j < F; j += NW) {  // y_e rows -> sYe (needed for b0p fold)
        const float* q = p.outW + (size_t)j * (2 * H) + H + lane * 8;
        float4 w0 = *(const float4*)q;
        float4 w1 = *(const float4*)(q + 4);
        float s = w0.x * e0.x + w0.y * e0.y + w0.z * e0.z + w0.w * e0.w
                + w1.x * e1.x + w1.y * e1.y + w1.z * e1.z + w1.w * e1.w;
        s = wredsum1(s);
        if (lane == 0) sYe[j] = s + p.outb[j];
      }
      {  // enc part of base0 (unaligned dW0 cols F..F+511 -> scalar)
        float sg[4];
#pragma unroll
        for (int g = 0; g < 4; ++g) {
          const float* q = p.dW0 + (size_t)(g * H + r) * (H + F) + F + lane * 8;
          sg[g] = q[0] * e0.x + q[1] * e0.y + q[2] * e0.z + q[3] * e0.w
                + q[4] * e1.x + q[5] * e1.y + q[6] * e1.z + q[7] * e1.w;
        }
        float4 v = wredsum4(make_float4(sg[0], sg[1], sg[2], sg[3]));
        if (lane == 0) {
          b0p[0] = v.x + p.dbih[0 * H + r] + p.dbhh[0 * H + r];
          b0p[1] = v.y + p.dbih[1 * H + r] + p.dbhh[1 * H + r];
          b0p[2] = v.z + p.dbih[2 * H + r] + p.dbhh[2 * H + r];
          b0p[3] = v.w + p.dbih[3 * H + r] + p.dbhh[3 * H + r];
        }
      }
      {  // prev_y part -> b00 (t=0 constant)
        float f0 = 0.f, f1 = 0.f, f2 = 0.f, f3 = 0.f;
        if (lane < F) {
          const float yv = p.py[lane];
          f0 = p.dW0[(size_t)(0 * H + r) * (H + F) + lane] * yv;
          f1 = p.dW0[(size_t)(1 * H + r) * (H + F) + lane] * yv;
          f2 = p.dW0[(size_t)(2 * H + r) * (H + F) + lane] * yv;
          f3 = p.dW0[(size_t)(3 * H + r) * (H + F) + lane] * yv;
        }
        float4 v = wredsum4(make_float4(f0, f1, f2, f3));
        if (lane == 0) {
          b00[0] = b0p[0] + v.x; b00[1] = b0p[1] + v.y;
          b00[2] = b0p[2] + v.z; b00[3] = b0p[3] + v.w;
        }
      }
      __syncthreads();  // sYe visible
      {  // fold dW0[:,:F] @ y_e into b0p (t>=1 constant)
        float f0 = 0.f, f1 = 0.f, f2 = 0.f, f3 = 0.f;
        if (lane < F) {
          const float yv = sYe[lane];
          f0 = p.dW0[(size_t)(0 * H + r) * (H + F) + lane] * yv;
          f1 = p.dW0[(size_t)(1 * H + r) * (H + F) + lane] * yv;
          f2 = p.dW0[(size_t)(2 * H + r) * (H + F) + lane] * yv;
          f3 = p.dW0[(size_t)(3 * H + r) * (H + F) + lane] * yv;
        }
        float4 v = wredsum4(make_float4(f0, f1, f2, f3));
        if (lane == 0) {
          b0p[0] += v.x; b0p[1] += v.y; b0p[2] += v.z; b0p[3] += v.w;
        }
      }
      fma8(wh2, e0, e1, sOld2);
    }

    // ---- Decoder t=0 S0: Whh0 @ h0_enc (still live in sBuf[0]) + b00. ----
    {
      W8 wh0 = ldw_g(p.dWhh, r, lane);
      float4 a0 = *(const float4*)(sBuf[0] + lane * 8);
      float4 a1 = *(const float4*)(sBuf[0] + lane * 8 + 4);
      float s[4] = {0.f, 0.f, 0.f, 0.f};
      fma8(wh0, a0, a1, s);
      float4 v = wredsum4(make_float4(s[0], s[1], s[2], s[3]));
      if (lane == 0) pub(&g_h[0][0][r], cellup(v, b00, c0), cidx(0, 0));
    }
    __syncthreads();  // WAR: S1(0) staging overwrites sBuf[0]

    // ---- Decoder main loop: 1 wait + 1 burst + 1 critical matvec per phase;
    //      all 128 producer blocks symmetric every phase. ----
    for (int t = 0; t < T; ++t) {
      const int pb = t & 1, ob = pb ^ 1;

      if (t >= 1) {  // S0: crit = M(LDS)@h2(t-1) + sOld0 + b0p
        W8 wh2 = ldw_g(p.dWhh + (size_t)8 * H * H, r, lane);  // prefetch (extra)
        cwait(cidx(t - 1, 2));
        ldvec(g_h[ob][2], sBuf[bi]);
        W8 wm = ldw_lds(sM, w, lane);
        float4 h20 = *(const float4*)(sBuf[bi] + lane * 8);
        float4 h21 = *(const float4*)(sBuf[bi] + lane * 8 + 4);
        float s[4] = {sOld0[0], sOld0[1], sOld0[2], sOld0[3]};
        fma8(wm, h20, h21, s);
        float4 v = wredsum4(make_float4(s[0], s[1], s[2], s[3]));
        if (lane == 0) pub(&g_h[pb][0][r], cellup(v, b0p, c0), cidx(t, 0));
        sOld2[0] = sOld2[1] = sOld2[2] = sOld2[3] = 0.f;
        fma8(wh2, h20, h21, sOld2);  // off-critical: for S2(t)
        bi ^= 1;
      }

      {  // S1: crit = dW1@h0(t) + sOld1; extra = Whh0@h0(t) -> sOld0 for S0(t+1)
        W8 wi  = ldw_g(p.dW1, r, lane);   // crit weights in flight during wait
        W8 wh0 = ldw_g(p.dWhh, r, lane);
        cwait(cidx(t, 0));
        ldvec(g_h[pb][0], sBuf[bi]);
        float4 a0 = *(const float4*)(sBuf[bi] + lane * 8);
        float4 a1 = *(const float4*)(sBuf[bi] + lane * 8 + 4);
        float s[4] = {sOld1[0], sOld1[1], sOld1[2], sOld1[3]};
        fma8(wi, a0, a1, s);
        float4 v = wredsum4(make_float4(s[0], s[1], s[2], s[3]));
        if (lane == 0) pub(&g_h[pb][1][r], cellup(v, b1s, c1), cidx(t, 1));
        sOld0[0] = sOld0[1] = sOld0[2] = sOld0[3] = 0.f;
        fma8(wh0, a0, a1, sOld0);
        bi ^= 1;
      }
      {  // S2: crit = dW2@h1(t) + sOld2; extra = Whh1@h1(t) -> sOld1 for S1(t+1)
        W8 wi  = ldw_g(p.dW2, r, lane);
        W8 wh1 = ldw_g(p.dWhh + (size_t)4 * H * H, r, lane);
        cwait(cidx(t, 1));
        ldvec(g_h[pb][1], sBuf[bi]);
        float4 a0 = *(const float4*)(sBuf[bi] + lane * 8);
        float4 a1 = *(const float4*)(sBuf[bi] + lane * 8 + 4);
        float s[4] = {sOld2[0], sOld2[1], sOld2[2], sOld2[3]};
        fma8(wi, a0, a1, s);
        float4 v = wredsum4(make_float4(s[0], s[1], s[2], s[3]));
        if (lane == 0) {
          float hv = cellup(v, b2s, c2);
          pub2(&g_h[pb][2][r], &g_hy[t][r], hv, cidx(t, 2));
        }
        sOld1[0] = sOld1[1] = sOld1[2] = sOld1[3] = 0.f;
        fma8(wh1, a0, a1, sOld1);
        bi ^= 1;
      }
    }
  }

  // ---- Exit: last block resets counters so graph replays start clean ----
  __syncthreads();
  if (threadIdx.x == 0) {
    unsigned old = __hip_atomic_fetch_add(&g_exit, 1u, __ATOMIC_RELAXED, SCOPE_AGENT);
    s_last = (old == NB - 1) ? 1 : 0;
  }
  __syncthreads();
  if (s_last) {
    for (int i = threadIdx.x; i < NC * CS; i += NT)
      __hip_atomic_store(&g_cnt[i], 0u, __ATOMIC_RELAXED, SCOPE_AGENT);
    if (threadIdx.x == 0)
      __hip_atomic_store(&g_exit, 0u, __ATOMIC_RELAXED, SCOPE_AGENT);
  }
}

extern "C" void kernel_launch(void* const* d_in, const int* in_sizes, int n_in,
                              void* d_out, int out_size, void* d_ws, size_t ws_size,
                              hipStream_t stream) {
  P p;
  p.x    = (const float*)d_in[0];
  p.py   = (const float*)d_in[1];
  p.eW0  = (const float*)d_in[2];
  p.eW1  = (const float*)d_in[3];
  p.eW2  = (const float*)d_in[4];
  // d_in[5] enc_Whh: unused (encoder runs one step from h=0)
  p.ebih = (const float*)d_in[6];
  p.ebhh = (const float*)d_in[7];
  // d_in[8..10] attn_W/attn_b/v_W: unused (softmax over length-1 axis == 1)
  p.dW0  = (const float*)d_in[11];
  p.dW1  = (const float*)d_in[12];
  p.dW2  = (const float*)d_in[13];
  p.dWhh = (const float*)d_in[14];
  p.dbih = (const float*)d_in[15];
  p.dbhh = (const float*)d_in[16];
  p.outW = (const float*)d_in[17];
  p.outb = (const float*)d_in[18];
  p.out  = (float*)d_out;

  hipLaunchKernelGGL(k_flow, dim3(NB), dim3(NT), 0, stream, p);
}

// Round 12
// 318.405 us; speedup vs baseline: 5.5254x; 5.5254x over previous
//
#include <hip/hip_runtime.h>
#include <cstddef>

constexpr int H  = 512;   // hidden
constexpr int F  = 21;    // features
constexpr int T  = 28;    // output steps
constexpr int PB = 128;   // producer blocks (R8-best geometry)
constexpr int NB = PB + 1;// + 1 dedicated y-writer block
constexpr int NT = 256;   // 4 waves/block -> 512 producer waves, 1 row/wave
constexpr int NW = NT / 64;

#define SCOPE_AGENT __HIP_MEMORY_SCOPE_AGENT

// Tagged cross-block state: (tag<<32)|float_bits. Publish = RMW exchange
// (immediate at coherence point, no release drain -> doesn't stall behind
// in-flight weight prefetches; R11's release-counter variant proved that
// cost). Per-element tags spread poll traffic across 128 LLC lines.
// Tag = producing decoder step t' + 2 (encoder-produced state: tag 1).
// g_hy is step-unique so the y-writer can never lose a WAR race.
__device__ unsigned long long g_hp[2][3][H];
__device__ unsigned long long g_hy[T][H];
__device__ unsigned g_exit;

struct P {
  const float *x, *py, *eW0, *eW1, *eW2, *ebih, *ebhh;
  const float *dW0, *dW1, *dW2, *dWhh, *dbih, *dbhh, *outW, *outb;
  float* out;
};

__device__ __forceinline__ float sigm(float v)  { return 1.0f / (1.0f + __expf(-v)); }
__device__ __forceinline__ float tanh_f(float v){ return 1.0f - 2.0f / (__expf(2.0f * v) + 1.0f); }

__device__ __forceinline__ float4 wredsum4(float4 v) {
#pragma unroll
  for (int off = 32; off > 0; off >>= 1) {
    v.x += __shfl_xor(v.x, off, 64);
    v.y += __shfl_xor(v.y, off, 64);
    v.z += __shfl_xor(v.z, off, 64);
    v.w += __shfl_xor(v.w, off, 64);
  }
  return v;
}
__device__ __forceinline__ float wredsum1(float v) {
#pragma unroll
  for (int off = 32; off > 0; off >>= 1) v += __shfl_xor(v, off, 64);
  return v;
}

__device__ __forceinline__ void pput(unsigned long long* slot, float v, unsigned tag) {
  union { float f; unsigned u; } c; c.f = v;
  unsigned long long pk = ((unsigned long long)tag << 32) | (unsigned long long)c.u;
  (void)__hip_atomic_exchange(slot, pk, __ATOMIC_RELAXED, SCOPE_AGENT);
}
__device__ __forceinline__ unsigned long long tld(const unsigned long long* q) {
  return __hip_atomic_load(q, __ATOMIC_RELAXED, SCOPE_AGENT);
}
__device__ __forceinline__ float fbits(unsigned long long v) {
  union { unsigned u; float f; } c; c.u = (unsigned)v; return c.f;
}

// Cooperative staged poll -> LDS: thread i owns elements {i, i+NT}; coalesced;
// both loads in flight per attempt; single trailing barrier.
__device__ __forceinline__ void stagev(const unsigned long long* __restrict__ A,
                                       unsigned wa, float* __restrict__ dst) {
  const int i = threadIdx.x;
  unsigned long long v0 = tld(A + i), v1 = tld(A + i + NT);
  int guard = 0;
  while ((((unsigned)(v0 >> 32)) != wa || ((unsigned)(v1 >> 32)) != wa) &&
         ++guard < (1 << 20)) {
    v0 = tld(A + i); v1 = tld(A + i + NT);
  }
  dst[i] = fbits(v0); dst[i + NT] = fbits(v1);
  __syncthreads();
}

// 4-gate weight fragment block: 8 float4 = 64B/lane per matrix.
struct W8 { float4 a[4]; float4 b[4]; };

__device__ __forceinline__ W8 ldw_g(const float* __restrict__ W, int r, int lane) {
  W8 o;
#pragma unroll
  for (int g = 0; g < 4; ++g) {
    const float* q = W + (size_t)(g * H + r) * H + lane * 8;
    o.a[g] = *(const float4*)q;
    o.b[g] = *(const float4*)(q + 4);
  }
  return o;
}
__device__ __forceinline__ W8 ldw_lds(const float* sM, int w, int lane) {
  W8 o;
#pragma unroll
  for (int g = 0; g < 4; ++g) {
    const float* q = sM + (w * 4 + g) * H + lane * 8;
    o.a[g] = *(const float4*)q;
    o.b[g] = *(const float4*)(q + 4);
  }
  return o;
}
__device__ __forceinline__ void fma8(const W8& wt, const float4& x0, const float4& x1,
                                     float s[4]) {
#pragma unroll
  for (int g = 0; g < 4; ++g) {
    s[g] += wt.a[g].x * x0.x + wt.a[g].y * x0.y + wt.a[g].z * x0.z + wt.a[g].w * x0.w
          + wt.b[g].x * x1.x + wt.b[g].y * x1.y + wt.b[g].z * x1.z + wt.b[g].w * x1.w;
  }
}

__device__ __forceinline__ float cellup(const float4& v, const float b[4], float& c) {
  float cn = sigm(v.y + b[1]) * c + sigm(v.x + b[0]) * tanh_f(v.z + b[2]);
  c = cn;
  return sigm(v.w + b[3]) * tanh_f(cn);
}

__device__ __forceinline__ void write_y_frag(const P& p, int trow, int w, int lane,
                                             const float4& h0, const float4& h1,
                                             const float* sYe) {
  for (int j = w; j < F; j += NW) {
    const float* q = p.outW + (size_t)j * (2 * H) + lane * 8;
    float4 w0 = *(const float4*)q;
    float4 w1 = *(const float4*)(q + 4);
    float s = w0.x * h0.x + w0.y * h0.y + w0.z * h0.z + w0.w * h0.w
            + w1.x * h1.x + w1.y * h1.y + w1.z * h1.z + w1.w * h1.w;
    s = wredsum1(s);
    if (lane == 0) p.out[trow * F + j] = s + sYe[j];
  }
}

__global__ __launch_bounds__(NT, 1)
void k_flow(P p) {
  const int lane = threadIdx.x & 63;
  const int w    = threadIdx.x >> 6;

  __shared__ float sM[NW * 4 * H];   // 32 KB: producer rows of M = dW0[:,:F]@outW_h
  __shared__ float sBuf[2][H];       // 4 KB: double-buffered staged vector
  __shared__ float senc[H];          // persistent encoder output
  __shared__ float sYe[F + 3];       // y_e = outW_e@enc + outb
  __shared__ int   s_last;

  if (blockIdx.x == PB) {
    // ================= Dedicated y-writer block (off critical path) ========
    stagev(g_hp[1][2], 1u, senc);
    {
      float4 e0 = *(const float4*)(senc + lane * 8);
      float4 e1 = *(const float4*)(senc + lane * 8 + 4);
      for (int j = w; j < F; j += NW) {
        const float* q = p.outW + (size_t)j * (2 * H) + H + lane * 8;
        float4 w0 = *(const float4*)q;
        float4 w1 = *(const float4*)(q + 4);
        float s = w0.x * e0.x + w0.y * e0.y + w0.z * e0.z + w0.w * e0.w
                + w1.x * e1.x + w1.y * e1.y + w1.z * e1.z + w1.w * e1.w;
        s = wredsum1(s);
        if (lane == 0) sYe[j] = s + p.outb[j];
      }
      __syncthreads();
    }
    for (int t = 0; t < T; ++t) {
      float* xb = sBuf[t & 1];
      stagev(g_hy[t], (unsigned)(t + 2), xb);  // h2(t), step-unique slot
      float4 h20 = *(const float4*)(xb + lane * 8);
      float4 h21 = *(const float4*)(xb + lane * 8 + 4);
      write_y_frag(p, t, w, lane, h20, h21, sYe);
    }
  } else {
    // ========================= Producer blocks =============================
    const int r = blockIdx.x * NW + w;  // 1 row/wave, fixed mapping (L2 locality)

    float c0 = 0.f, c1 = 0.f, c2 = 0.f;
    float b00[4], b0p[4], b1s[4], b2s[4];  // lane-0-meaningful biases
    float sOld0[4] = {0, 0, 0, 0}, sOld1[4] = {0, 0, 0, 0}, sOld2[4] = {0, 0, 0, 0};
    int bi = 0;

    // ---- Encoder layer 0: h=c=0 -> Whh zero, f-gate dead. Publish tag 1. ----
    {
      float s0 = 0.f, s1 = 0.f, s2 = 0.f, s3 = 0.f;
      if (lane < F) {
        const float xv = p.x[lane];
        s0 = p.eW0[(size_t)(0 * H + r) * F + lane] * xv;
        s1 = p.eW0[(size_t)(1 * H + r) * F + lane] * xv;
        s2 = p.eW0[(size_t)(2 * H + r) * F + lane] * xv;
        s3 = p.eW0[(size_t)(3 * H + r) * F + lane] * xv;
      }
      float4 v = wredsum4(make_float4(s0, s1, s2, s3));
      if (lane == 0) {
        const float* bi_ = p.ebih + r;
        const float* bh_ = p.ebhh + r;
        float cn = sigm(v.x + bi_[0] + bh_[0]) * tanh_f(v.z + bi_[2 * H] + bh_[2 * H]);
        c0 = cn;
        pput(&g_hp[1][0][r], sigm(v.w + bi_[3 * H] + bh_[3 * H]) * tanh_f(cn), 1u);
      }
    }

    // ---- Build sM while other blocks finish enc0 (input-independent) ----
    {
      float4 mA[4], mB[4];
#pragma unroll
      for (int g = 0; g < 4; ++g) {
        mA[g] = make_float4(0.f, 0.f, 0.f, 0.f);
        mB[g] = make_float4(0.f, 0.f, 0.f, 0.f);
      }
      for (int f = 0; f < F; ++f) {
        const float* q = p.outW + (size_t)f * (2 * H) + lane * 8;
        const float4 oa = *(const float4*)q;
        const float4 ob = *(const float4*)(q + 4);
#pragma unroll
        for (int g = 0; g < 4; ++g) {
          const float wf = p.dW0[(size_t)(g * H + r) * (H + F) + f];
          mA[g].x += wf * oa.x; mA[g].y += wf * oa.y; mA[g].z += wf * oa.z; mA[g].w += wf * oa.w;
          mB[g].x += wf * ob.x; mB[g].y += wf * ob.y; mB[g].z += wf * ob.z; mB[g].w += wf * ob.w;
        }
      }
#pragma unroll
      for (int g = 0; g < 4; ++g) {
        *(float4*)(sM + (w * 4 + g) * H + lane * 8)     = mA[g];
        *(float4*)(sM + (w * 4 + g) * H + lane * 8 + 4) = mB[g];
      }
    }
#pragma unroll
    for (int g = 0; g < 4; ++g) {
      b1s[g] = p.dbih[4 * H + g * H + r] + p.dbhh[4 * H + g * H + r];
      b2s[g] = p.dbih[8 * H + g * H + r] + p.dbhh[8 * H + g * H + r];
    }

    // ---- Encoder layer 1 (stages h0_enc into sBuf[0]; kept for decoder t=0) ----
    {
      W8 wt = ldw_g(p.eW1, r, lane);  // prefetch before poll
      stagev(g_hp[1][0], 1u, sBuf[0]);
      float4 a0 = *(const float4*)(sBuf[0] + lane * 8);
      float4 a1 = *(const float4*)(sBuf[0] + lane * 8 + 4);
      float s[4] = {0.f, 0.f, 0.f, 0.f};
      fma8(wt, a0, a1, s);
      float4 v = wredsum4(make_float4(s[0], s[1], s[2], s[3]));
      if (lane == 0) {
        const float* bi_ = p.ebih + 4 * H + r;
        const float* bh_ = p.ebhh + 4 * H + r;
        float cn = sigm(v.x + bi_[0] + bh_[0]) * tanh_f(v.z + bi_[2 * H] + bh_[2 * H]);
        c1 = cn;
        pput(&g_hp[1][1][r], sigm(v.w + bi_[3 * H] + bh_[3 * H]) * tanh_f(cn), 1u);
      }
    }

    // ---- Encoder layer 2 -> enc_out; extra: sOld1 = Whh1@h1_enc (for S1(0)) ----
    {
      W8 wt  = ldw_g(p.eW2, r, lane);
      W8 wh1 = ldw_g(p.dWhh + (size_t)4 * H * H, r, lane);
      stagev(g_hp[1][1], 1u, sBuf[1]);
      float4 a0 = *(const float4*)(sBuf[1] + lane * 8);
      float4 a1 = *(const float4*)(sBuf[1] + lane * 8 + 4);
      float s[4] = {0.f, 0.f, 0.f, 0.f};
      fma8(wt, a0, a1, s);
      float4 v = wredsum4(make_float4(s[0], s[1], s[2], s[3]));
      if (lane == 0) {
        const float* bi_ = p.ebih + 8 * H + r;
        const float* bh_ = p.ebhh + 8 * H + r;
        float cn = sigm(v.x + bi_[0] + bh_[0]) * tanh_f(v.z + bi_[2 * H] + bh_[2 * H]);
        c2 = cn;
        pput(&g_hp[1][2][r], sigm(v.w + bi_[3 * H] + bh_[3 * H]) * tanh_f(cn), 1u);
      }
      fma8(wh1, a0, a1, sOld1);
    }

    // ---- Setup: senc, y_e, base0 constants; extra: sOld2 = Whh2@enc ----
    {
      W8 wh2 = ldw_g(p.dWhh + (size_t)8 * H * H, r, lane);
      stagev(g_hp[1][2], 1u, senc);   // senc persists (read-only afterwards)
      float4 e0 = *(const float4*)(senc + lane * 8);
      float4 e1 = *(const float4*)(senc + lane * 8 + 4);
      for (int j = w; j < F; j += NW) {  // y_e rows -> sYe (needed for b0p fold)
        const float* q = p.outW + (size_t)j * (2 * H) + H + lane * 8;
        float4 w0 = *(const float4*)q;
        float4 w1 = *(const float4*)(q + 4);
        float s = w0.x * e0.x + w0.y * e0.y + w0.z * e0.z + w0.w * e0.w
                + w1.x * e1.x + w1.y * e1.y + w1.z * e1.z + w1.w * e1.w;
        s = wredsum1(s);
        if (lane == 0) sYe[j] = s + p.outb[j];
      }
      {  // enc part of base0 (unaligned dW0 cols F..F+511 -> scalar)
        float sg[4];
#pragma unroll
        for (int g = 0; g < 4; ++g) {
          const float* q = p.dW0 + (size_t)(g * H + r) * (H + F) + F + lane * 8;
          sg[g] = q[0] * e0.x + q[1] * e0.y + q[2] * e0.z + q[3] * e0.w
                + q[4] * e1.x + q[5] * e1.y + q[6] * e1.z + q[7] * e1.w;
        }
        float4 v = wredsum4(make_float4(sg[0], sg[1], sg[2], sg[3]));
        if (lane == 0) {
          b0p[0] = v.x + p.dbih[0 * H + r] + p.dbhh[0 * H + r];
          b0p[1] = v.y + p.dbih[1 * H + r] + p.dbhh[1 * H + r];
          b0p[2] = v.z + p.dbih[2 * H + r] + p.dbhh[2 * H + r];
          b0p[3] = v.w + p.dbih[3 * H + r] + p.dbhh[3 * H + r];
        }
      }
      {  // prev_y part -> b00 (t=0 constant)
        float f0 = 0.f, f1 = 0.f, f2 = 0.f, f3 = 0.f;
        if (lane < F) {
          const float yv = p.py[lane];
          f0 = p.dW0[(size_t)(0 * H + r) * (H + F) + lane] * yv;
          f1 = p.dW0[(size_t)(1 * H + r) * (H + F) + lane] * yv;
          f2 = p.dW0[(size_t)(2 * H + r) * (H + F) + lane] * yv;
          f3 = p.dW0[(size_t)(3 * H + r) * (H + F) + lane] * yv;
        }
        float4 v = wredsum4(make_float4(f0, f1, f2, f3));
        if (lane == 0) {
          b00[0] = b0p[0] + v.x; b00[1] = b0p[1] + v.y;
          b00[2] = b0p[2] + v.z; b00[3] = b0p[3] + v.w;
        }
      }
      __syncthreads();  // sYe visible
      {  // fold dW0[:,:F] @ y_e into b0p (t>=1 constant)
        float f0 = 0.f, f1 = 0.f, f2 = 0.f, f3 = 0.f;
        if (lane < F) {
          const float yv = sYe[lane];
          f0 = p.dW0[(size_t)(0 * H + r) * (H + F) + lane] * yv;
          f1 = p.dW0[(size_t)(1 * H + r) * (H + F) + lane] * yv;
          f2 = p.dW0[(size_t)(2 * H + r) * (H + F) + lane] * yv;
          f3 = p.dW0[(size_t)(3 * H + r) * (H + F) + lane] * yv;
        }
        float4 v = wredsum4(make_float4(f0, f1, f2, f3));
        if (lane == 0) {
          b0p[0] += v.x; b0p[1] += v.y; b0p[2] += v.z; b0p[3] += v.w;
        }
      }
      fma8(wh2, e0, e1, sOld2);
    }

    // ---- Decoder t=0 S0: Whh0 @ h0_enc (still live in sBuf[0]) + b00. No poll. ----
    {
      W8 wh0 = ldw_g(p.dWhh, r, lane);
      float4 a0 = *(const float4*)(sBuf[0] + lane * 8);
      float4 a1 = *(const float4*)(sBuf[0] + lane * 8 + 4);
      float s[4] = {0.f, 0.f, 0.f, 0.f};
      fma8(wh0, a0, a1, s);
      float4 v = wredsum4(make_float4(s[0], s[1], s[2], s[3]));
      if (lane == 0) pput(&g_hp[0][0][r], cellup(v, b00, c0), 2u);
    }
    __syncthreads();  // WAR: S1(0) staging overwrites sBuf[0]

    // ---- Decoder main loop: 1 poll + 1 critical matvec per phase;
    //      all 128 producer blocks perfectly symmetric every phase. ----
    for (int t = 0; t < T; ++t) {
      const int pb = t & 1, ob = pb ^ 1;
      const unsigned wn = (unsigned)(t + 2);
      const unsigned wo = (unsigned)(t + 1);

      if (t >= 1) {  // S0: crit = M(LDS)@h2(t-1) + sOld0 + b0p
        W8 wh2 = ldw_g(p.dWhh + (size_t)8 * H * H, r, lane);  // prefetch (extra)
        stagev(g_hp[ob][2], wo, sBuf[bi]);
        W8 wm = ldw_lds(sM, w, lane);
        float4 h20 = *(const float4*)(sBuf[bi] + lane * 8);
        float4 h21 = *(const float4*)(sBuf[bi] + lane * 8 + 4);
        float s[4] = {sOld0[0], sOld0[1], sOld0[2], sOld0[3]};
        fma8(wm, h20, h21, s);
        float4 v = wredsum4(make_float4(s[0], s[1], s[2], s[3]));
        if (lane == 0) pput(&g_hp[pb][0][r], cellup(v, b0p, c0), wn);
        sOld2[0] = sOld2[1] = sOld2[2] = sOld2[3] = 0.f;
        fma8(wh2, h20, h21, sOld2);  // off-critical: for S2(t)
        bi ^= 1;
      }

      {  // S1: crit = dW1@h0(t) + sOld1; extra = Whh0@h0(t) -> sOld0 for S0(t+1)
        W8 wi  = ldw_g(p.dW1, r, lane);   // crit weights in flight during poll
        W8 wh0 = ldw_g(p.dWhh, r, lane);
        stagev(g_hp[pb][0], wn, sBuf[bi]);
        float4 a0 = *(const float4*)(sBuf[bi] + lane * 8);
        float4 a1 = *(const float4*)(sBuf[bi] + lane * 8 + 4);
        float s[4] = {sOld1[0], sOld1[1], sOld1[2], sOld1[3]};
        fma8(wi, a0, a1, s);
        float4 v = wredsum4(make_float4(s[0], s[1], s[2], s[3]));
        if (lane == 0) pput(&g_hp[pb][1][r], cellup(v, b1s, c1), wn);
        sOld0[0] = sOld0[1] = sOld0[2] = sOld0[3] = 0.f;
        fma8(wh0, a0, a1, sOld0);
        bi ^= 1;
      }
      {  // S2: crit = dW2@h1(t) + sOld2; extra = Whh1@h1(t) -> sOld1 for S1(t+1)
        W8 wi  = ldw_g(p.dW2, r, lane);
        W8 wh1 = ldw_g(p.dWhh + (size_t)4 * H * H, r, lane);
        stagev(g_hp[pb][1], wn, sBuf[bi]);
        float4 a0 = *(const float4*)(sBuf[bi] + lane * 8);
        float4 a1 = *(const float4*)(sBuf[bi] + lane * 8 + 4);
        float s[4] = {sOld2[0], sOld2[1], sOld2[2], sOld2[3]};
        fma8(wi, a0, a1, s);
        float4 v = wredsum4(make_float4(s[0], s[1], s[2], s[3]));
        if (lane == 0) {
          float hv = cellup(v, b2s, c2);
          pput(&g_hp[pb][2][r], hv, wn);   // main chain first
          pput(&g_hy[t][r], hv, wn);       // y-writer copy (step-unique slot)
        }
        sOld1[0] = sOld1[1] = sOld1[2] = sOld1[3] = 0.f;
        fma8(wh1, a0, a1, sOld1);
        bi ^= 1;
      }
    }
  }

  // ---- Exit: last block resets all tags so graph replays start clean ----
  __syncthreads();
  if (threadIdx.x == 0) {
    unsigned old = __hip_atomic_fetch_add(&g_exit, 1u, __ATOMIC_RELAXED, SCOPE_AGENT);
    s_last = (old == NB - 1) ? 1 : 0;
  }
  __syncthreads();
  if (s_last) {
    unsigned long long* z = &g_hp[0][0][0];
    for (int i = threadIdx.x; i < 2 * 3 * H; i += NT)
      __hip_atomic_store(z + i, 0ull, __ATOMIC_RELAXED, SCOPE_AGENT);
    unsigned long long* y = &g_hy[0][0];
    for (int i = threadIdx.x; i < T * H; i += NT)
      __hip_atomic_store(y + i, 0ull, __ATOMIC_RELAXED, SCOPE_AGENT);
    if (threadIdx.x == 0)
      __hip_atomic_store(&g_exit, 0u, __ATOMIC_RELAXED, SCOPE_AGENT);
  }
}

extern "C" void kernel_launch(void* const* d_in, const int* in_sizes, int n_in,
                              void* d_out, int out_size, void* d_ws, size_t ws_size,
                              hipStream_t stream) {
  P p;
  p.x    = (const float*)d_in[0];
  p.py   = (const float*)d_in[1];
  p.eW0  = (const float*)d_in[2];
  p.eW1  = (const float*)d_in[3];
  p.eW2  = (const float*)d_in[4];
  // d_in[5] enc_Whh: unused (encoder runs one step from h=0)
  p.ebih = (const float*)d_in[6];
  p.ebhh = (const float*)d_in[7];
  // d_in[8..10] attn_W/attn_b/v_W: unused (softmax over length-1 axis == 1)
  p.dW0  = (const float*)d_in[11];
  p.dW1  = (const float*)d_in[12];
  p.dW2  = (const float*)d_in[13];
  p.dWhh = (const float*)d_in[14];
  p.dbih = (const float*)d_in[15];
  p.dbhh = (const float*)d_in[16];
  p.outW = (const float*)d_in[17];
  p.outb = (const float*)d_in[18];
  p.out  = (float*)d_out;

  hipLaunchKernelGGL(k_flow, dim3(NB), dim3(NT), 0, stream, p);
}